// Round 7
// baseline (61.251 us; speedup 1.0000x reference)
//
#include <hip/hip_runtime.h>

#define S_LEN 2048
#define B_DIM 32
#define H_DIM 1024
#define ROWS 8       // s-rows per wave in energy kernel
#define KSPLIT 8     // k-split partials in proj
#define KCH (H_DIM / KSPLIT)  // 128

typedef float fx4 __attribute__((ext_vector_type(4)));

// ---------------------------------------------------------------------------
// Kernel 1: vp[kp,b,h] = sum_{k in chunk kp} dec[b,k] * W[k,h]
// Grid: (1, B, KSPLIT) = 256 blocks x 256 threads = 1 block/CU.
// Thread t owns 4 consecutive h via fx4: one 16-B coalesced W load feeds
// 4 FMAs; 128 fx4 loads/thread -> 4x fewer latency slots and 4x more bytes
// in flight than the scalar version for the HBM-cold W fetch (W is evicted
// from L3 every replay by the 256 MiB enc stream).
// dec loads are block-uniform -> s_load.
// ---------------------------------------------------------------------------
__global__ __launch_bounds__(256) void proj_kernel(
    const float* __restrict__ dec, const float* __restrict__ W,
    float* __restrict__ vp)
{
    const int t  = threadIdx.x;          // h4 index: h = 4t
    const int b  = blockIdx.y;
    const int kp = blockIdx.z;
    const int k0 = kp * KCH;
    const float* __restrict__ drow = dec + (size_t)b * H_DIM;

    fx4 acc = {0.f, 0.f, 0.f, 0.f};
#pragma unroll 8
    for (int kk = 0; kk < KCH; ++kk) {
        const int k = k0 + kk;
        const fx4 w = reinterpret_cast<const fx4*>(W + (size_t)k * H_DIM)[t];
        acc += drow[k] * w;              // uniform scalar -> s_load
    }

    reinterpret_cast<fx4*>(vp + ((size_t)kp * B_DIM + b) * H_DIM)[t] = acc;
}

// ---------------------------------------------------------------------------
// Kernel 2: e[b,s] = dot(enc[s,b,:], v[b,:]),  v = sum of 8 partials.
// Grid: (B/4, S/ROWS) = (8, 256) = 2048 blocks.
// XCD-contiguous swizzle: HW round-robins linear id across 8 XCDs; remap
// logical = (id%8)*256 + id/8 so each XCD walks a CONTIGUOUS 32-MB enc
// range sequentially (instead of a 16KB-per-128KB strided slice).
// All 32 enc float4 loads issued upfront (a[8][4], compile-time indices,
// ~170 VGPR, no scratch) -> no mid-kernel latency bubble. 8 interleaved
// reduce chains; lane 0 stores two fx4.
// ---------------------------------------------------------------------------
__global__ __launch_bounds__(256) void energy_kernel(
    const float* __restrict__ enc, const float* __restrict__ vp,
    float* __restrict__ e)
{
    const int lane = threadIdx.x & 63;
    const int wv   = threadIdx.x >> 6;

    const int id      = blockIdx.y * 8 + blockIdx.x;   // dispatch-linear
    const int logical = (id & 7) * 256 + (id >> 3);    // XCD-contiguous
    const int xg      = logical & 7;                   // b-group
    const int sg      = logical >> 3;                  // s-group

    const int b  = xg * 4 + wv;
    const int s0 = sg * ROWS;

    // v[b,:] fragment: sum KSPLIT partials (L2-resident, ~0.4us/128MB)
    fx4 vf[4];
#pragma unroll
    for (int i = 0; i < 4; ++i) {
        fx4 t = {0.f, 0.f, 0.f, 0.f};
#pragma unroll
        for (int kp = 0; kp < KSPLIT; ++kp) {
            const fx4* __restrict__ p = reinterpret_cast<const fx4*>(
                vp + ((size_t)kp * B_DIM + b) * H_DIM);
            t += p[lane + 64 * i];
        }
        vf[i] = t;
    }

    // all 32 enc loads in flight before any dot-product consumes them
    fx4 a[ROWS][4];
#pragma unroll
    for (int r = 0; r < ROWS; ++r) {
        const fx4* __restrict__ ep = reinterpret_cast<const fx4*>(
            enc + ((size_t)(s0 + r) * B_DIM + b) * H_DIM);
#pragma unroll
        for (int i = 0; i < 4; ++i)
            a[r][i] = ep[lane + 64 * i];
    }

    float acc[ROWS];
#pragma unroll
    for (int r = 0; r < ROWS; ++r) {
        float t = 0.f;
#pragma unroll
        for (int i = 0; i < 4; ++i)
            t += a[r][i].x * vf[i].x + a[r][i].y * vf[i].y +
                 a[r][i].z * vf[i].z + a[r][i].w * vf[i].w;
        acc[r] = t;
    }

#pragma unroll
    for (int off = 32; off; off >>= 1) {
#pragma unroll
        for (int r = 0; r < ROWS; ++r)
            acc[r] += __shfl_xor(acc[r], off, 64);
    }

    if (lane == 0) {
        fx4 o0, o1;
        o0.x = acc[0]; o0.y = acc[1]; o0.z = acc[2]; o0.w = acc[3];
        o1.x = acc[4]; o1.y = acc[5]; o1.z = acc[6]; o1.w = acc[7];
        fx4* ep = reinterpret_cast<fx4*>(e + (size_t)b * S_LEN + s0);
        ep[0] = o0;
        ep[1] = o1;
    }
}

// ---------------------------------------------------------------------------
// Kernel 3: out[b,0,s] = softmax_s(e[b,s]).  One block per b (32 blocks).
// Bias term c[b] omitted: constant per row, softmax-invariant.
// ---------------------------------------------------------------------------
__global__ __launch_bounds__(256) void softmax_kernel(
    const float* __restrict__ e, float* __restrict__ out)
{
    __shared__ float red[4];
    const int b    = blockIdx.x;
    const int tid  = threadIdx.x;
    const int lane = tid & 63;
    const int wv   = tid >> 6;
    const float* __restrict__ row = e + (size_t)b * S_LEN;

    float vals[8];
    float m = -1e30f;
#pragma unroll
    for (int i = 0; i < 8; ++i) {
        vals[i] = row[tid + 256 * i];
        m = fmaxf(m, vals[i]);
    }
#pragma unroll
    for (int off = 32; off; off >>= 1)
        m = fmaxf(m, __shfl_xor(m, off, 64));
    if (lane == 0) red[wv] = m;
    __syncthreads();
    m = fmaxf(fmaxf(red[0], red[1]), fmaxf(red[2], red[3]));

    float sum = 0.0f;
#pragma unroll
    for (int i = 0; i < 8; ++i) {
        vals[i] = __expf(vals[i] - m);
        sum += vals[i];
    }
#pragma unroll
    for (int off = 32; off; off >>= 1)
        sum += __shfl_xor(sum, off, 64);
    __syncthreads();                 // red reuse hazard
    if (lane == 0) red[wv] = sum;
    __syncthreads();
    sum = red[0] + red[1] + red[2] + red[3];

    const float inv = 1.0f / sum;
#pragma unroll
    for (int i = 0; i < 8; ++i)
        out[(size_t)b * S_LEN + tid + 256 * i] = vals[i] * inv;
}

// ---------------------------------------------------------------------------
extern "C" void kernel_launch(void* const* d_in, const int* in_sizes, int n_in,
                              void* d_out, int out_size, void* d_ws, size_t ws_size,
                              hipStream_t stream)
{
    const float* dec = (const float*)d_in[0];   // [B,H]
    const float* enc = (const float*)d_in[1];   // [S,B,H]
    const float* W   = (const float*)d_in[2];   // [H,H]
    // d_in[3] = bias: constant-per-row contribution, softmax-invariant -> unused
    float* out = (float*)d_out;                 // [B,1,S] flat

    float* vp = (float*)d_ws;                   // KSPLIT*B*H floats (1 MiB)
    float* e  = vp + KSPLIT * B_DIM * H_DIM;    // B*S floats (256 KiB)

    proj_kernel<<<dim3(1, B_DIM, KSPLIT), 256, 0, stream>>>(dec, W, vp);
    energy_kernel<<<dim3(B_DIM / 4, S_LEN / ROWS), 256, 0, stream>>>(enc, vp, e);
    softmax_kernel<<<B_DIM, 256, 0, stream>>>(e, out);
}